// Round 1
// 829.505 us; speedup vs baseline: 1.2752x; 1.2752x over previous
//
#include <hip/hip_runtime.h>
#include <stdint.h>

// TGN recommender fused pipeline — fp16 MFMA variant.
// Sizes (fixed by the problem):
#define BATCH   262144
#define DMEM    100       // memory dim
#define AS      456       // LDS A row stride (elements): 448 used + 8 pad

typedef float    f32x4 __attribute__((ext_vector_type(4)));
typedef _Float16 f16x8 __attribute__((ext_vector_type(8)));
typedef unsigned short u16x4 __attribute__((ext_vector_type(4)));

__device__ __forceinline__ unsigned short f2h(float f) {
  union { _Float16 h; unsigned short u; } v; v.h = (_Float16)f;  // RNE
  return v.u;
}
__device__ __forceinline__ float h2f(unsigned short u) {
  union { _Float16 h; unsigned short u; } v; v.u = u; return (float)v.h;
}

#define MFMA16(A, B, C) __builtin_amdgcn_mfma_f32_16x16x32_f16((A), (B), (C), 0, 0, 0)

// ---------------------------------------------------------------------------
// Prep: pack weights into MFMA B-operand fragment order (fp16).
// Main GEMM op list (270 ops), A columns: [0:304)=x (src|dst|msg|t_enc),
// [304:320)=0, [320:420)=h, [420:448)=0.
//   phase1: kc 0..9  (K 0:320),  nt 0..18 (cols 0:304)  -> W_ih[col][k]
//   phase2: kc 10..13 (K 320:448), nt 0..12 (cols 0:208) -> W_hh[col][k-320], col<200
//   phase3: kc 10..13,            nt 19..25 (cols 304:416)-> W_hh[200+(col-304)][k-320]
// op index: o<190: kc=o/19, nt=o%19 ; else o2=o-190: kc=10+o2/20, p=o2%20,
//           nt = p<13 ? p : p+6.
// W1 ops (16): kc 0..3 (K=128 over h_new), nt 0..3 (64 cols).
// B-fragment layout for v_mfma_f32_16x16x32_f16: lane holds B[k][n],
// n=lane&15, k=(lane>>4)*8+j  -> frag[o][lane][j].
// Also zeroes stats_g (replaces the hipMemsetAsync dispatch).
// ---------------------------------------------------------------------------
__global__ void prep_kernel(const float* __restrict__ W_ih, const float* __restrict__ W_hh,
                            const float* __restrict__ W1,
                            const float* __restrict__ b_ih, const float* __restrict__ b_hh,
                            unsigned short* __restrict__ Bfrag,
                            unsigned short* __restrict__ W1frag,
                            float* __restrict__ biasbuf,
                            float* __restrict__ stats_g) {
  int blk = blockIdx.x;
  int tid = threadIdx.x;
  if (blk == 72) {                       // fused biases + stats zero
    if (tid < 128) stats_g[tid] = 0.f;
    if (tid < 100) {
      biasbuf[tid]       = b_ih[tid]       + b_hh[tid];        // r
      biasbuf[100 + tid] = b_ih[100 + tid] + b_hh[100 + tid];  // z
      biasbuf[200 + tid] = b_ih[200 + tid];                    // i_n
      biasbuf[300 + tid] = b_hh[200 + tid];                    // h_n
    }
    return;
  }
  int o = blk * 4 + (tid >> 6);
  if (o >= 286) return;
  int lane = tid & 63, quad = lane >> 4, l15 = lane & 15;
  if (o < 270) {
    int kc, nt;
    if (o < 190) { kc = o / 19; nt = o % 19; }
    else { int o2 = o - 190; kc = 10 + o2 / 20; int p = o2 % 20; nt = (p < 13) ? p : p + 6; }
    int col = nt * 16 + l15;
    unsigned short* dst = Bfrag + (size_t)o * 512 + lane * 8;
    for (int j = 0; j < 8; ++j) {
      int kg = kc * 32 + quad * 8 + j;
      float v = 0.f;
      if (kc < 10) {
        if (kg < 304 && col < 300) v = W_ih[col * 304 + kg];
      } else {
        int kl = kg - 320;
        if (nt < 13) { if (kl < 100 && col < 200) v = W_hh[col * 100 + kl]; }
        else { int hd = col - 304; if (kl < 100 && hd < 100) v = W_hh[(200 + hd) * 100 + kl]; }
      }
      dst[j] = f2h(v);
    }
  } else {
    int o1 = o - 270;
    int kc = o1 >> 2, nt = o1 & 3;
    int col = nt * 16 + l15;
    unsigned short* dst = W1frag + (size_t)o1 * 512 + lane * 8;
    for (int j = 0; j < 8; ++j) {
      int kg = kc * 32 + quad * 8 + j;
      dst[j] = f2h((kg < 100) ? W1[col * 100 + kg] : 0.f);
    }
  }
}

// ---------------------------------------------------------------------------
// Main fused kernel: 64 rows/block, 256 threads (4 waves: wi=row-half, wj=nt-parity).
// v2 changes vs previous session's kernel:
//  * A-staging gathers are float4 (25 x 16B per 400B memory row) issued as a
//    19-deep independent run per thread -> ~19KB/wave in flight vs ~256B
//    before (the kernel was gather-latency bound at 1.4 TB/s).
//  * B fragments are loaded global->VGPR directly (Bfrag layout is already a
//    coalesced 16B/lane load); Bsec LDS staging and all 28 in-loop
//    __syncthreads() (each a vmcnt(0) drain) are removed. Per-parity op lists
//    are statically unrolled so acc[] indexing stays compile-time (no scratch).
// LDS 71.7 KB -> still 2 blocks/CU; VGPR budget 256 at 2 waves/SIMD.
// ---------------------------------------------------------------------------
__global__ __launch_bounds__(256, 2)
void main_kernel(const int* __restrict__ n_id, const float* __restrict__ memory,
                 const int* __restrict__ last_update,
                 const int* __restrict__ store_src, const int* __restrict__ store_dst,
                 const int* __restrict__ store_t, const float* __restrict__ store_msg,
                 const float* __restrict__ time_w, const float* __restrict__ time_b,
                 const float* __restrict__ b1,
                 const unsigned short* __restrict__ Bfrag,
                 const unsigned short* __restrict__ W1frag,
                 const float* __restrict__ biasbuf,
                 unsigned short* __restrict__ a_ws, float* __restrict__ stats_g) {
  __shared__ __align__(16) unsigned short A_lds[64 * AS];  // 58368 B
  __shared__ __align__(16) unsigned short hbuf[64 * 100];  // 12800 B
  __shared__ float stats[128];                             // 512 B

  const int tid  = threadIdx.x;
  const int wave = tid >> 6;
  const int lane = tid & 63;
  const int quad = lane >> 4;
  const int l15  = lane & 15;
  const int wi   = wave >> 1;   // 0/1: rows [32wi, 32wi+32)
  const int wj   = wave & 1;    // nt parity
  const int blk  = blockIdx.x;

  if (tid < 128) stats[tid] = 0.f;

  // ---- stage A tile: vectorized gathers + time encoding, fp16 into LDS ----
  {
    const int r = tid >> 2;           // row 0..63
    const int p = tid & 3;            // quarter 0..3
    const int b = blk * 64 + r;
    const int n = n_id[b];
    const int sidx = store_src[n];
    const int didx = store_dst[n];
    const float dtf = (float)(store_t[n] - last_update[n]);
    const float* ms = memory + (size_t)sidx * DMEM;
    const float* md = memory + (size_t)didx * DMEM;
    const float* mh = memory + (size_t)n * DMEM;
    unsigned short* Ar = A_lds + r * AS;

    // 76 float4 units per row spread over the 4 quarter-threads:
    //   v = 4*i + p ; a = v/25 selects {src,dst,h}, c = v%25 the chunk.
    //   unit v==75 is a dummy (re-loads mh[0:4], lands in pad col 448).
    // All 19 loads issued before any conversion/ds_write -> deep MLP.
    f32x4 vals[19];
    int   offs[19];
    #pragma unroll
    for (int i = 0; i < 19; ++i) {
      const int v = i * 4 + p;
      const int a = v / 25;
      const int c = v - a * 25;
      const float* bp = (a == 0) ? ms : ((a == 1) ? md : mh);
      vals[i] = *(const f32x4*)(bp + c * 4);
      offs[i] = (a == 0) ? (c * 4)
              : ((a == 1) ? (100 + c * 4)
              : ((a == 2) ? (320 + c * 4) : 448));
    }
    #pragma unroll
    for (int i = 0; i < 19; ++i) {
      u16x4 h4 = { f2h(vals[i][0]), f2h(vals[i][1]), f2h(vals[i][2]), f2h(vals[i][3]) };
      *(u16x4*)(Ar + offs[i]) = h4;    // 8B aligned: AS*2=912, offs*2 all %8==0
    }

    // t_enc (cols 204:304): 25 cos per thread
    const int d0 = p * 25;
    for (int i = 0; i < 25; ++i) {
      const int d = d0 + i;
      Ar[204 + d] = f2h(cosf(dtf * time_w[d] + time_b[d]));
    }

    if (p == 0) {                       // raw_msg (cols 200:204)
      f32x4 mg = *(const f32x4*)(store_msg + (size_t)n * 4);
      u16x4 m4 = { f2h(mg[0]), f2h(mg[1]), f2h(mg[2]), f2h(mg[3]) };
      *(u16x4*)(Ar + 200) = m4;
    } else if (p == 1) {                // zero pad [304:320)
      uint4 z4 = {0u, 0u, 0u, 0u};
      *(uint4*)(Ar + 304) = z4;
      *(uint4*)(Ar + 312) = z4;
    } else if (p == 2) {                // zero pad [420:436)
      u16x4 z = {0, 0, 0, 0};
      *(u16x4*)(Ar + 420) = z; *(u16x4*)(Ar + 424) = z;
      *(u16x4*)(Ar + 428) = z; *(u16x4*)(Ar + 432) = z;
    } else {                            // zero pad [436:448)
      u16x4 z = {0, 0, 0, 0};
      *(u16x4*)(Ar + 436) = z; *(u16x4*)(Ar + 440) = z; *(u16x4*)(Ar + 444) = z;
    }
  }

  f32x4 acc[13][2];
  #pragma unroll
  for (int t = 0; t < 13; ++t)
    for (int m = 0; m < 2; ++m) acc[t][m] = f32x4{0.f, 0.f, 0.f, 0.f};

  __syncthreads();                      // A fully staged

  // ---- main GEMM: B fragments straight from global (L2-hot), no barriers ----
  const unsigned short* Arow0 = A_lds + (wi * 32 + l15) * AS;
  const unsigned short* Arow1 = Arow0 + 16 * AS;
  const size_t boff = (size_t)lane * 8;

  if (wj == 0) {
    #pragma unroll 2
    for (int kc = 0; kc < 10; ++kc) {             // phase1: ops kc*19 + {0,2,..,18}
      const int kb = kc * 32 + quad * 8;
      f16x8 af0 = __builtin_bit_cast(f16x8, *(const uint4*)(Arow0 + kb));
      f16x8 af1 = __builtin_bit_cast(f16x8, *(const uint4*)(Arow1 + kb));
      const unsigned short* Bp = Bfrag + (size_t)(kc * 19) * 512 + boff;
      #pragma unroll
      for (int t = 0; t < 10; ++t) {
        f16x8 bfr = *(const f16x8*)(Bp + (size_t)(2 * t) * 512);
        acc[t][0] = MFMA16(af0, bfr, acc[t][0]);
        acc[t][1] = MFMA16(af1, bfr, acc[t][1]);
      }
    }
    #pragma unroll 2
    for (int kc = 10; kc < 14; ++kc) {            // phase2/3: even p
      const int kb = kc * 32 + quad * 8;
      f16x8 af0 = __builtin_bit_cast(f16x8, *(const uint4*)(Arow0 + kb));
      f16x8 af1 = __builtin_bit_cast(f16x8, *(const uint4*)(Arow1 + kb));
      const unsigned short* Bp = Bfrag + (size_t)(190 + (kc - 10) * 20) * 512 + boff;
      #pragma unroll
      for (int t = 0; t < 10; ++t) {
        const int p  = 2 * t;                     // 0..18 even
        const int tl = (p < 13) ? (p >> 1) : ((p + 6) >> 1);   // {0..6,10,11,12}
        f16x8 bfr = *(const f16x8*)(Bp + (size_t)p * 512);
        acc[tl][0] = MFMA16(af0, bfr, acc[tl][0]);
        acc[tl][1] = MFMA16(af1, bfr, acc[tl][1]);
      }
    }
  } else {
    #pragma unroll 2
    for (int kc = 0; kc < 10; ++kc) {             // phase1: ops kc*19 + {1,3,..,17}
      const int kb = kc * 32 + quad * 8;
      f16x8 af0 = __builtin_bit_cast(f16x8, *(const uint4*)(Arow0 + kb));
      f16x8 af1 = __builtin_bit_cast(f16x8, *(const uint4*)(Arow1 + kb));
      const unsigned short* Bp = Bfrag + (size_t)(kc * 19) * 512 + boff;
      #pragma unroll
      for (int t = 0; t < 9; ++t) {
        f16x8 bfr = *(const f16x8*)(Bp + (size_t)(2 * t + 1) * 512);
        acc[t][0] = MFMA16(af0, bfr, acc[t][0]);
        acc[t][1] = MFMA16(af1, bfr, acc[t][1]);
      }
    }
    #pragma unroll 2
    for (int kc = 10; kc < 14; ++kc) {            // phase2/3: odd p
      const int kb = kc * 32 + quad * 8;
      f16x8 af0 = __builtin_bit_cast(f16x8, *(const uint4*)(Arow0 + kb));
      f16x8 af1 = __builtin_bit_cast(f16x8, *(const uint4*)(Arow1 + kb));
      const unsigned short* Bp = Bfrag + (size_t)(190 + (kc - 10) * 20) * 512 + boff;
      #pragma unroll
      for (int t = 0; t < 10; ++t) {
        const int p  = 2 * t + 1;                 // 1..19 odd
        const int tl = (p < 13) ? (p >> 1) : ((p + 6) >> 1);   // {0..5,9,10,11,12}
        f16x8 bfr = *(const f16x8*)(Bp + (size_t)p * 512);
        acc[tl][0] = MFMA16(af0, bfr, acc[tl][0]);
        acc[tl][1] = MFMA16(af1, bfr, acc[tl][1]);
      }
    }
  }
  __syncthreads();                      // all A-fragment reads done

  // ---- copy h (A cols 320:420) into hbuf before the acc dump overwrites A ----
  for (int i = 0; i < 25; ++i) {
    int e = tid + 256 * i;                             // 0..6399
    hbuf[e] = A_lds[(e / 100) * AS + 320 + (e % 100)];
  }
  __syncthreads();

  // ---- dump accumulators (pre-activation gates) to LDS as fp16 ----
  #pragma unroll
  for (int t = 0; t < 13; ++t) {
    int col = (t * 2 + wj) * 16 + l15;                 // < 416
    #pragma unroll
    for (int m = 0; m < 2; ++m) {
      int rbase = wi * 32 + m * 16 + quad * 4;
      #pragma unroll
      for (int rr = 0; rr < 4; ++rr)
        A_lds[(rbase + rr) * AS + col] = f2h(acc[t][m][rr]);
    }
  }
  __syncthreads();

  // ---- GRU gates -> h_new (fp16, into cols 0:100) ----
  // NOTE: cols 100..127 are intentionally NOT zeroed for the W1 GEMM: W1frag
  // has exact 0.0 weights for kg>=100, so stale (finite) preacts contribute
  // 0*v = 0. A zeroing loop here previously RACED with the Gr[100+d] reads
  // of slower waves in this same barrier epoch (the round-1/2 absmax ~0.2 bug).
  for (int i = 0; i < 25; ++i) {
    int e = tid + 256 * i;
    int r = e / 100, d = e % 100;
    const unsigned short* Gr = A_lds + r * AS;
    float s_r = h2f(Gr[d])       + biasbuf[d];
    float s_z = h2f(Gr[100 + d]) + biasbuf[100 + d];
    float i_n = h2f(Gr[200 + d]) + biasbuf[200 + d];
    float h_n = h2f(Gr[304 + d]) + biasbuf[300 + d];
    float h   = h2f(hbuf[r * 100 + d]);
    float rg = 1.f / (1.f + __expf(-s_r));
    float zg = 1.f / (1.f + __expf(-s_z));
    float nn = tanhf(i_n + rg * h_n);
    float hw = (1.f - zg) * nn + zg * h;
    A_lds[r * AS + d] = f2h(hw);
  }
  __syncthreads();

  // ---- a = relu(h_new @ W1^T + b1): K=128 (4 kc), N=64 (wave takes 2 nt) ----
  f32x4 aacc[2][2];
  #pragma unroll
  for (int m = 0; m < 2; ++m)
    for (int t = 0; t < 2; ++t) aacc[m][t] = f32x4{0.f, 0.f, 0.f, 0.f};
  for (int k4 = 0; k4 < 4; ++k4) {
    int kb = k4 * 32 + quad * 8;
    f16x8 a0 = __builtin_bit_cast(f16x8, *(const uint4*)(Arow0 + kb));
    f16x8 a1 = __builtin_bit_cast(f16x8, *(const uint4*)(Arow1 + kb));
    #pragma unroll
    for (int t = 0; t < 2; ++t) {
      int nt = wj * 2 + t;
      f16x8 bfr = *(const f16x8*)(W1frag + (size_t)(k4 * 4 + nt) * 512 + boff);
      aacc[0][t] = MFMA16(a0, bfr, aacc[0][t]);
      aacc[1][t] = MFMA16(a1, bfr, aacc[1][t]);
    }
  }

  // ---- +b1, relu, BN partial stats, store a (fp16) ----
  float ssum[2] = {0.f, 0.f}, ssq[2] = {0.f, 0.f};
  #pragma unroll
  for (int t = 0; t < 2; ++t) {
    int col = (wj * 2 + t) * 16 + l15;
    float bb = b1[col];
    #pragma unroll
    for (int m = 0; m < 2; ++m) {
      int rbase = wi * 32 + m * 16 + quad * 4;
      #pragma unroll
      for (int rr = 0; rr < 4; ++rr) {
        float v = fmaxf(aacc[m][t][rr] + bb, 0.f);
        ssum[t] += v; ssq[t] += v * v;
        a_ws[(size_t)(blk * 64 + rbase + rr) * 64 + col] = f2h(v);
      }
    }
  }
  #pragma unroll
  for (int t = 0; t < 2; ++t) {
    ssum[t] += __shfl_xor(ssum[t], 16); ssum[t] += __shfl_xor(ssum[t], 32);
    ssq[t]  += __shfl_xor(ssq[t], 16);  ssq[t]  += __shfl_xor(ssq[t], 32);
  }
  if (quad == 0) {
    #pragma unroll
    for (int t = 0; t < 2; ++t) {
      int col = (wj * 2 + t) * 16 + l15;
      atomicAdd(&stats[col], ssum[t]);
      atomicAdd(&stats[64 + col], ssq[t]);
    }
  }
  __syncthreads();
  if (tid < 128) atomicAdd(&stats_g[tid], stats[tid]);   // one atomic/channel/block
}

// ---------------------------------------------------------------------------
// Output: fold BN (mu, var, gamma, beta) + W2/b2 into out = a.w_c + C_c.
// ---------------------------------------------------------------------------
__global__ __launch_bounds__(256)
void out_kernel(const unsigned short* __restrict__ a_ws, const float* __restrict__ stats_g,
                const float* __restrict__ gamma, const float* __restrict__ beta,
                const float* __restrict__ W2, const float* __restrict__ b2,
                float* __restrict__ out) {
  __shared__ float w0[64], w1[64], cpart[128];
  __shared__ float C0s, C1s;
  int tid = threadIdx.x;
  if (tid < 64) {
    const float invB = 1.f / (float)BATCH;
    float mu  = stats_g[tid] * invB;
    float var = stats_g[64 + tid] * invB - mu * mu;
    float g   = gamma[tid] * rsqrtf(var + 1e-5f);
    w0[tid] = g * W2[tid];
    w1[tid] = g * W2[64 + tid];
    float t = beta[tid] - mu * g;
    cpart[tid]      = t * W2[tid];
    cpart[64 + tid] = t * W2[64 + tid];
  }
  __syncthreads();
  if (tid == 0) {
    float c0 = b2[0], c1 = b2[1];
    for (int j = 0; j < 64; ++j) { c0 += cpart[j]; c1 += cpart[64 + j]; }
    C0s = c0; C1s = c1;
  }
  __syncthreads();
  int b = blockIdx.x * 256 + tid;
  const uint4* ap = (const uint4*)(a_ws + (size_t)b * 64);
  float o0 = C0s, o1 = C1s;
  #pragma unroll
  for (int i = 0; i < 8; ++i) {
    uint4 v = ap[i];
    unsigned int uu[4] = {v.x, v.y, v.z, v.w};
    #pragma unroll
    for (int q = 0; q < 4; ++q) {
      float lo = h2f((unsigned short)(uu[q] & 0xffffu));
      float hi = h2f((unsigned short)(uu[q] >> 16));
      int j = i * 8 + q * 2;
      o0 += lo * w0[j] + hi * w0[j + 1];
      o1 += lo * w1[j] + hi * w1[j + 1];
    }
  }
  *(float2*)(out + (size_t)b * 2) = make_float2(o0, o1);
}

// ---------------------------------------------------------------------------
extern "C" void kernel_launch(void* const* d_in, const int* in_sizes, int n_in,
                              void* d_out, int out_size, void* d_ws, size_t ws_size,
                              hipStream_t stream) {
  const int*   n_id   = (const int*)d_in[0];
  const float* memory = (const float*)d_in[1];
  const int*   last_u = (const int*)d_in[2];
  const int*   s_src  = (const int*)d_in[3];
  const int*   s_dst  = (const int*)d_in[4];
  const int*   s_t    = (const int*)d_in[5];
  const float* s_msg  = (const float*)d_in[6];
  const float* time_w = (const float*)d_in[7];
  const float* time_b = (const float*)d_in[8];
  const float* W_ih   = (const float*)d_in[9];
  const float* b_ih   = (const float*)d_in[10];
  const float* W_hh   = (const float*)d_in[11];
  const float* b_hh   = (const float*)d_in[12];
  const float* W1     = (const float*)d_in[13];
  const float* b1     = (const float*)d_in[14];
  const float* gamma  = (const float*)d_in[15];
  const float* beta   = (const float*)d_in[16];
  const float* W2     = (const float*)d_in[17];
  const float* b2     = (const float*)d_in[18];

  char* ws = (char*)d_ws;
  float*          stats_g = (float*)ws;                                   // 512 B
  float*          biasbuf = (float*)(ws + 512);                           // 1600 B
  unsigned short* Bfrag   = (unsigned short*)(ws + 4096);                 // 270 KiB
  unsigned short* W1frag  = (unsigned short*)(ws + 4096 + 276480);        // 16 KiB
  unsigned short* a_ws    = (unsigned short*)(ws + (1u << 20));           // 32 MiB

  prep_kernel<<<73, 256, 0, stream>>>(W_ih, W_hh, W1, b_ih, b_hh, Bfrag, W1frag,
                                      biasbuf, stats_g);
  main_kernel<<<4096, 256, 0, stream>>>(n_id, memory, last_u, s_src, s_dst, s_t,
                                        s_msg, time_w, time_b, b1,
                                        Bfrag, W1frag, biasbuf, a_ws, stats_g);
  out_kernel<<<1024, 256, 0, stream>>>(a_ws, stats_g, gamma, beta, W2, b2, (float*)d_out);
}

// Round 2
// 749.860 us; speedup vs baseline: 1.4107x; 1.1062x over previous
//
#include <hip/hip_runtime.h>
#include <stdint.h>

// TGN recommender fused pipeline — fp16 MFMA variant.
#define BATCH   262144
#define DMEM    100       // memory dim
#define AS      456       // LDS A row stride (elements): 448 used + 8 pad

typedef float    f32x4 __attribute__((ext_vector_type(4)));
typedef _Float16 f16x8 __attribute__((ext_vector_type(8)));
typedef unsigned short u16x4 __attribute__((ext_vector_type(4)));

__device__ __forceinline__ unsigned short f2h(float f) {
  union { _Float16 h; unsigned short u; } v; v.h = (_Float16)f;  // RNE
  return v.u;
}
__device__ __forceinline__ float h2f(unsigned short u) {
  union { _Float16 h; unsigned short u; } v; v.u = u; return (float)v.h;
}

#define MFMA16(A, B, C) __builtin_amdgcn_mfma_f32_16x16x32_f16((A), (B), (C), 0, 0, 0)

// ---------------------------------------------------------------------------
// Per-wave nt (output column tile) partition for the main GEMM.
// Op counts per nt: nt 0..12 -> 14 ops (10 phase1 + 4 p23); nt 13..18 -> 10
// (phase1 only); nt 19..25 -> 4 (p23 only). The partition below balances to
// 68/68/66/68 ops per wave and dedups B reads (each op read ONCE per block).
// ---------------------------------------------------------------------------
namespace wcfg {
constexpr int NT[4][7] = {
  {0, 1, 2, 3, 19, 20, 21},
  {4, 5, 6, 7, 22, 23, 24},
  {8, 9, 10, 11, 13, 13, 13},   // padding repeats guarded by LEN
  {12, 14, 15, 16, 17, 18, 25}};
constexpr int LEN[4] = {7, 7, 5, 7};
}

// ---------------------------------------------------------------------------
// Prep: pack weights into MFMA B-operand fragment order (fp16).
// Main GEMM op list (270 ops), A columns: [0:304)=x (src|dst|msg|t_enc),
// [304:320)=0, [320:420)=h, [420:448)=0.
//   phase1: kc 0..9  (K 0:320),  nt 0..18 (cols 0:304)  -> W_ih[col][k]
//   phase2: kc 10..13 (K 320:448), nt 0..12 (cols 0:208) -> W_hh[col][k-320], col<200
//   phase3: kc 10..13,            nt 19..25 (cols 304:416)-> W_hh[200+(col-304)][k-320]
// op index: o<190: kc=o/19, nt=o%19 ; else o2=o-190: kc=10+o2/20, p=o2%20,
//           nt = p<13 ? p : p+6.
// W1 ops (16): kc 0..3 (K=128 over h_new), nt 0..3 (64 cols).
// B-fragment layout for v_mfma_f32_16x16x32_f16: lane holds B[k][n],
// n=lane&15, k=(lane>>4)*8+j  -> frag[o][lane][j].
// Also zeroes stats_g (replaces the hipMemsetAsync dispatch).
// ---------------------------------------------------------------------------
__global__ void prep_kernel(const float* __restrict__ W_ih, const float* __restrict__ W_hh,
                            const float* __restrict__ W1,
                            const float* __restrict__ b_ih, const float* __restrict__ b_hh,
                            unsigned short* __restrict__ Bfrag,
                            unsigned short* __restrict__ W1frag,
                            float* __restrict__ biasbuf,
                            float* __restrict__ stats_g) {
  int blk = blockIdx.x;
  int tid = threadIdx.x;
  if (blk == 72) {                       // fused biases + stats zero
    if (tid < 128) stats_g[tid] = 0.f;
    if (tid < 100) {
      biasbuf[tid]       = b_ih[tid]       + b_hh[tid];        // r
      biasbuf[100 + tid] = b_ih[100 + tid] + b_hh[100 + tid];  // z
      biasbuf[200 + tid] = b_ih[200 + tid];                    // i_n
      biasbuf[300 + tid] = b_hh[200 + tid];                    // h_n
    }
    return;
  }
  int o = blk * 4 + (tid >> 6);
  if (o >= 286) return;
  int lane = tid & 63, quad = lane >> 4, l15 = lane & 15;
  if (o < 270) {
    int kc, nt;
    if (o < 190) { kc = o / 19; nt = o % 19; }
    else { int o2 = o - 190; kc = 10 + o2 / 20; int p = o2 % 20; nt = (p < 13) ? p : p + 6; }
    int col = nt * 16 + l15;
    unsigned short* dst = Bfrag + (size_t)o * 512 + lane * 8;
    for (int j = 0; j < 8; ++j) {
      int kg = kc * 32 + quad * 8 + j;
      float v = 0.f;
      if (kc < 10) {
        if (kg < 304 && col < 300) v = W_ih[col * 304 + kg];
      } else {
        int kl = kg - 320;
        if (nt < 13) { if (kl < 100 && col < 200) v = W_hh[col * 100 + kl]; }
        else { int hd = col - 304; if (kl < 100 && hd < 100) v = W_hh[(200 + hd) * 100 + kl]; }
      }
      dst[j] = f2h(v);
    }
  } else {
    int o1 = o - 270;
    int kc = o1 >> 2, nt = o1 & 3;
    int col = nt * 16 + l15;
    unsigned short* dst = W1frag + (size_t)o1 * 512 + lane * 8;
    for (int j = 0; j < 8; ++j) {
      int kg = kc * 32 + quad * 8 + j;
      dst[j] = f2h((kg < 100) ? W1[col * 100 + kg] : 0.f);
    }
  }
}

// ---------------------------------------------------------------------------
// GEMM helpers (templated on wave id so acc indexing stays compile-time).
// ---------------------------------------------------------------------------
template<int W>
__device__ __forceinline__ void b_prefetch0(f16x8 (&bq)[7],
    const unsigned short* __restrict__ Bfrag, size_t boff) {
  constexpr auto& NT = wcfg::NT[W];
  constexpr int L = wcfg::LEN[W];
  #pragma unroll
  for (int t = 0; t < 7; ++t)
    if (t < L && NT[t] < 19)
      bq[t] = *(const f16x8*)(Bfrag + (size_t)NT[t] * 512 + boff);
}

template<int W>
__device__ __forceinline__ void gemm_core(f32x4 (&acc)[7][4], f16x8 (&bq)[7],
    const unsigned short* __restrict__ Bfrag, const unsigned short* Arow,
    int quad, size_t boff) {
  constexpr auto& NT = wcfg::NT[W];
  constexpr int L = wcfg::LEN[W];
  // ---- phase1: kc 0..9 (K 0:320), members nt<19. B(kc+1) loads pipelined
  //      in registers while MFMAs of kc run (no barriers in this loop). ----
  #pragma unroll
  for (int kc = 0; kc < 10; ++kc) {
    const int kb = kc * 32 + quad * 8;
    f16x8 af[4];
    #pragma unroll
    for (int m = 0; m < 4; ++m)
      af[m] = __builtin_bit_cast(f16x8, *(const uint4*)(Arow + m * 16 * AS + kb));
    f16x8 bn[7];
    if (kc < 9) {
      const unsigned short* Bk = Bfrag + (size_t)(kc + 1) * 19 * 512 + boff;
      #pragma unroll
      for (int t = 0; t < 7; ++t)
        if (t < L && NT[t] < 19)
          bn[t] = *(const f16x8*)(Bk + (size_t)NT[t] * 512);
    } else {                       // prefetch p23 kc=10 ops
      const unsigned short* Bk = Bfrag + (size_t)190 * 512 + boff;
      #pragma unroll
      for (int t = 0; t < 7; ++t)
        if (t < L && (NT[t] < 13 || NT[t] >= 19))
          bn[t] = *(const f16x8*)(Bk + (size_t)((NT[t] < 13) ? NT[t] : NT[t] - 6) * 512);
    }
    #pragma unroll
    for (int t = 0; t < 7; ++t)
      if (t < L && NT[t] < 19) {
        #pragma unroll
        for (int m = 0; m < 4; ++m)
          acc[t][m] = MFMA16(af[m], bq[t], acc[t][m]);
      }
    if (kc < 9) {
      #pragma unroll
      for (int t = 0; t < 7; ++t)
        if (t < L && NT[t] < 19) bq[t] = bn[t];
    } else {
      #pragma unroll
      for (int t = 0; t < 7; ++t)
        if (t < L && (NT[t] < 13 || NT[t] >= 19)) bq[t] = bn[t];
    }
  }
  // ---- phase2/3: kc 10..13 (K 320:448), members nt<13 || nt>=19 ----
  #pragma unroll
  for (int kc = 10; kc < 14; ++kc) {
    const int kb = kc * 32 + quad * 8;
    f16x8 af[4];
    #pragma unroll
    for (int m = 0; m < 4; ++m)
      af[m] = __builtin_bit_cast(f16x8, *(const uint4*)(Arow + m * 16 * AS + kb));
    f16x8 bn[7];
    if (kc < 13) {
      const unsigned short* Bk = Bfrag + (size_t)(190 + (kc - 9) * 20) * 512 + boff;
      #pragma unroll
      for (int t = 0; t < 7; ++t)
        if (t < L && (NT[t] < 13 || NT[t] >= 19))
          bn[t] = *(const f16x8*)(Bk + (size_t)((NT[t] < 13) ? NT[t] : NT[t] - 6) * 512);
    }
    #pragma unroll
    for (int t = 0; t < 7; ++t)
      if (t < L && (NT[t] < 13 || NT[t] >= 19)) {
        #pragma unroll
        for (int m = 0; m < 4; ++m)
          acc[t][m] = MFMA16(af[m], bq[t], acc[t][m]);
      }
    if (kc < 13) {
      #pragma unroll
      for (int t = 0; t < 7; ++t)
        if (t < L && (NT[t] < 13 || NT[t] >= 19)) bq[t] = bn[t];
    }
  }
}

template<int W>
__device__ __forceinline__ void dump_acc(const f32x4 (&acc)[7][4],
    unsigned short* A_lds, int quad, int l15) {
  constexpr auto& NT = wcfg::NT[W];
  constexpr int L = wcfg::LEN[W];
  #pragma unroll
  for (int t = 0; t < 7; ++t)
    if (t < L) {
      const int col = NT[t] * 16 + l15;
      #pragma unroll
      for (int m = 0; m < 4; ++m) {
        const int rbase = m * 16 + quad * 4;
        #pragma unroll
        for (int rr = 0; rr < 4; ++rr)
          A_lds[(rbase + rr) * AS + col] = f2h(acc[t][m][rr]);
      }
    }
}

// ---------------------------------------------------------------------------
// Main fused kernel: 64 rows/block, 256 threads (4 waves).
// v3: each wave owns a disjoint nt set over ALL 64 rows (acc[7][4]) so every
// B fragment is read once per block (L2 traffic halved, vmem issues halved),
// GEMM is barrier-free with register-pipelined B; cos overlaps gather
// latency; gates use __expf + v_rcp; biasbuf staged in LDS.
// LDS 73.3 KB -> 2 blocks/CU.
// ---------------------------------------------------------------------------
__global__ __launch_bounds__(256, 2)
void main_kernel(const int* __restrict__ n_id, const float* __restrict__ memory,
                 const int* __restrict__ last_update,
                 const int* __restrict__ store_src, const int* __restrict__ store_dst,
                 const int* __restrict__ store_t, const float* __restrict__ store_msg,
                 const float* __restrict__ time_w, const float* __restrict__ time_b,
                 const float* __restrict__ b1,
                 const unsigned short* __restrict__ Bfrag,
                 const unsigned short* __restrict__ W1frag,
                 const float* __restrict__ biasbuf,
                 unsigned short* __restrict__ a_ws, float* __restrict__ stats_g) {
  __shared__ __align__(16) unsigned short A_lds[64 * AS];  // 58368 B
  __shared__ __align__(16) unsigned short hbuf[64 * 100];  // 12800 B
  __shared__ float bias_lds[400];                          // 1600 B
  __shared__ float stats[128];                             // 512 B

  const int tid  = threadIdx.x;
  const int wave = tid >> 6;
  const int lane = tid & 63;
  const int quad = lane >> 4;
  const int l15  = lane & 15;
  const int blk  = blockIdx.x;
  const size_t boff = (size_t)lane * 8;

  if (tid < 128) stats[tid] = 0.f;
  if (tid < 200) {                       // stage fused biases to LDS
    bias_lds[tid]       = biasbuf[tid];
    bias_lds[200 + tid] = biasbuf[200 + tid];
  }

  // ---- stage A tile: vectorized gathers + time encoding, fp16 into LDS ----
  {
    const int r = tid >> 2;           // row 0..63
    const int p = tid & 3;            // quarter 0..3
    const int b = blk * 64 + r;
    const int n = n_id[b];
    const int sidx = store_src[n];
    const int didx = store_dst[n];
    const int stt  = store_t[n];
    const int lu   = last_update[n];
    const float* ms = memory + (size_t)sidx * DMEM;
    const float* md = memory + (size_t)didx * DMEM;
    const float* mh = memory + (size_t)n * DMEM;
    unsigned short* Ar = A_lds + r * AS;

    // 76 float4 units per row spread over 4 quarter-threads; unit 75 is a
    // dummy (mh[0:4] -> pad col 448). All 19 loads issued first (deep MLP).
    f32x4 vals[19];
    #pragma unroll
    for (int i = 0; i < 19; ++i) {
      const int v = i * 4 + p;
      const int a = v / 25;
      const int c = v - a * 25;
      const float* bp = (a == 0) ? ms : ((a == 1) ? md : mh);
      vals[i] = *(const f32x4*)(bp + c * 4);
    }
    f32x4 mg;
    if (p == 0) mg = *(const f32x4*)(store_msg + (size_t)n * 4);

    // t_enc (cols 204:304) computed WHILE gathers are in flight
    const float dtf = (float)(stt - lu);
    const int d0 = p * 25;
    for (int i = 0; i < 25; ++i) {
      const int d = d0 + i;
      Ar[204 + d] = f2h(cosf(dtf * time_w[d] + time_b[d]));
    }
    if (p == 0) {                       // raw_msg (cols 200:204)
      u16x4 m4 = { f2h(mg[0]), f2h(mg[1]), f2h(mg[2]), f2h(mg[3]) };
      *(u16x4*)(Ar + 200) = m4;
    } else if (p == 1) {                // zero pad [304:320)
      uint4 z4 = {0u, 0u, 0u, 0u};
      *(uint4*)(Ar + 304) = z4;
      *(uint4*)(Ar + 312) = z4;
    } else if (p == 2) {                // zero pad [420:436)
      u16x4 z = {0, 0, 0, 0};
      *(u16x4*)(Ar + 420) = z; *(u16x4*)(Ar + 424) = z;
      *(u16x4*)(Ar + 428) = z; *(u16x4*)(Ar + 432) = z;
    } else {                            // zero pad [436:448)
      u16x4 z = {0, 0, 0, 0};
      *(u16x4*)(Ar + 436) = z; *(u16x4*)(Ar + 440) = z; *(u16x4*)(Ar + 444) = z;
    }
    // consume gathers (vmcnt waits land here, after the cos work)
    #pragma unroll
    for (int i = 0; i < 19; ++i) {
      const int v = i * 4 + p;
      const int a = v / 25;
      const int c = v - a * 25;
      const int off = (a == 0) ? (c * 4)
                    : ((a == 1) ? (100 + c * 4)
                    : ((a == 2) ? (320 + c * 4) : 448));
      u16x4 h4 = { f2h(vals[i][0]), f2h(vals[i][1]), f2h(vals[i][2]), f2h(vals[i][3]) };
      *(u16x4*)(Ar + off) = h4;       // 8B aligned (AS*2=912, off*2 %8==0)
    }
  }

  f32x4 acc[7][4];
  #pragma unroll
  for (int t = 0; t < 7; ++t)
    #pragma unroll
    for (int m = 0; m < 4; ++m) acc[t][m] = f32x4{0.f, 0.f, 0.f, 0.f};

  f16x8 bq[7];
  switch (wave) {                        // issue kc=0 B loads before barrier
    case 0: b_prefetch0<0>(bq, Bfrag, boff); break;
    case 1: b_prefetch0<1>(bq, Bfrag, boff); break;
    case 2: b_prefetch0<2>(bq, Bfrag, boff); break;
    default: b_prefetch0<3>(bq, Bfrag, boff); break;
  }
  __syncthreads();                       // A fully staged

  const unsigned short* Arow = A_lds + l15 * AS;
  switch (wave) {
    case 0: gemm_core<0>(acc, bq, Bfrag, Arow, quad, boff); break;
    case 1: gemm_core<1>(acc, bq, Bfrag, Arow, quad, boff); break;
    case 2: gemm_core<2>(acc, bq, Bfrag, Arow, quad, boff); break;
    default: gemm_core<3>(acc, bq, Bfrag, Arow, quad, boff); break;
  }
  __syncthreads();                       // all A-fragment reads done

  // ---- copy h (A cols 320:420) into hbuf before the acc dump overwrites A ----
  for (int i = 0; i < 25; ++i) {
    int e = tid + 256 * i;                             // 0..6399
    hbuf[e] = A_lds[(e / 100) * AS + 320 + (e % 100)];
  }
  __syncthreads();

  // ---- dump accumulators (pre-activation gates) to LDS as fp16 ----
  switch (wave) {
    case 0: dump_acc<0>(acc, A_lds, quad, l15); break;
    case 1: dump_acc<1>(acc, A_lds, quad, l15); break;
    case 2: dump_acc<2>(acc, A_lds, quad, l15); break;
    default: dump_acc<3>(acc, A_lds, quad, l15); break;
  }

  // W1 B fragments: issue now so the loads complete under the gates phase.
  f16x8 wb[4];
  #pragma unroll
  for (int k4 = 0; k4 < 4; ++k4)
    wb[k4] = *(const f16x8*)(W1frag + (size_t)(k4 * 4 + wave) * 512 + boff);

  __syncthreads();                       // dump visible

  // ---- GRU gates -> h_new (fp16, into cols 0:100) ----
  // NOTE: cols 100..127 are intentionally NOT zeroed for the W1 GEMM: W1frag
  // has exact 0.0 weights for kg>=100, so stale (finite) preacts contribute
  // 0*v = 0. A zeroing loop here would RACE with the Gr[100+d] reads of
  // slower waves in this same barrier epoch.
  for (int i = 0; i < 25; ++i) {
    int e = tid + 256 * i;
    int r = e / 100, d = e % 100;
    const unsigned short* Gr = A_lds + r * AS;
    float s_r = h2f(Gr[d])       + bias_lds[d];
    float s_z = h2f(Gr[100 + d]) + bias_lds[100 + d];
    float i_n = h2f(Gr[200 + d]) + bias_lds[200 + d];
    float h_n = h2f(Gr[304 + d]) + bias_lds[300 + d];
    float h   = h2f(hbuf[r * 100 + d]);
    float rg = __builtin_amdgcn_rcpf(1.f + __expf(-s_r));
    float zg = __builtin_amdgcn_rcpf(1.f + __expf(-s_z));
    float x2 = i_n + rg * h_n;
    x2 = fminf(fmaxf(x2, -30.f), 30.f);            // keep e2 finite
    float e2 = __expf(-2.f * x2);
    float nn = (1.f - e2) * __builtin_amdgcn_rcpf(1.f + e2);   // tanh(x2)
    float hw = (1.f - zg) * nn + zg * h;
    A_lds[r * AS + d] = f2h(hw);
  }
  __syncthreads();

  // ---- a = relu(h_new @ W1^T + b1): K=128 (4 kc); wave w owns col tile w ----
  f32x4 aacc[4];
  #pragma unroll
  for (int m = 0; m < 4; ++m) aacc[m] = f32x4{0.f, 0.f, 0.f, 0.f};
  #pragma unroll
  for (int k4 = 0; k4 < 4; ++k4) {
    const int kb = k4 * 32 + quad * 8;
    #pragma unroll
    for (int m = 0; m < 4; ++m) {
      f16x8 a = __builtin_bit_cast(f16x8, *(const uint4*)(Arow + m * 16 * AS + kb));
      aacc[m] = MFMA16(a, wb[k4], aacc[m]);
    }
  }

  // ---- +b1, relu, BN partial stats, store a (fp16) ----
  const int col = wave * 16 + l15;
  const float bb = b1[col];
  float ssum = 0.f, ssq = 0.f;
  #pragma unroll
  for (int m = 0; m < 4; ++m) {
    const int rbase = m * 16 + quad * 4;
    #pragma unroll
    for (int rr = 0; rr < 4; ++rr) {
      float v = fmaxf(aacc[m][rr] + bb, 0.f);
      ssum += v; ssq += v * v;
      a_ws[(size_t)(blk * 64 + rbase + rr) * 64 + col] = f2h(v);
    }
  }
  ssum += __shfl_xor(ssum, 16); ssum += __shfl_xor(ssum, 32);
  ssq  += __shfl_xor(ssq, 16);  ssq  += __shfl_xor(ssq, 32);
  if (quad == 0) {
    atomicAdd(&stats[col], ssum);
    atomicAdd(&stats[64 + col], ssq);
  }
  __syncthreads();
  if (tid < 128) atomicAdd(&stats_g[tid], stats[tid]);   // one atomic/channel/block
}

// ---------------------------------------------------------------------------
// Output: fold BN (mu, var, gamma, beta) + W2/b2 into out = a.w_c + C_c.
// ---------------------------------------------------------------------------
__global__ __launch_bounds__(256)
void out_kernel(const unsigned short* __restrict__ a_ws, const float* __restrict__ stats_g,
                const float* __restrict__ gamma, const float* __restrict__ beta,
                const float* __restrict__ W2, const float* __restrict__ b2,
                float* __restrict__ out) {
  __shared__ float w0[64], w1[64], cpart[128];
  __shared__ float C0s, C1s;
  int tid = threadIdx.x;
  if (tid < 64) {
    const float invB = 1.f / (float)BATCH;
    float mu  = stats_g[tid] * invB;
    float var = stats_g[64 + tid] * invB - mu * mu;
    float g   = gamma[tid] * rsqrtf(var + 1e-5f);
    w0[tid] = g * W2[tid];
    w1[tid] = g * W2[64 + tid];
    float t = beta[tid] - mu * g;
    cpart[tid]      = t * W2[tid];
    cpart[64 + tid] = t * W2[64 + tid];
  }
  __syncthreads();
  if (tid == 0) {
    float c0 = b2[0], c1 = b2[1];
    for (int j = 0; j < 64; ++j) { c0 += cpart[j]; c1 += cpart[64 + j]; }
    C0s = c0; C1s = c1;
  }
  __syncthreads();
  int b = blockIdx.x * 256 + tid;
  const uint4* ap = (const uint4*)(a_ws + (size_t)b * 64);
  float o0 = C0s, o1 = C1s;
  #pragma unroll
  for (int i = 0; i < 8; ++i) {
    uint4 v = ap[i];
    unsigned int uu[4] = {v.x, v.y, v.z, v.w};
    #pragma unroll
    for (int q = 0; q < 4; ++q) {
      float lo = h2f((unsigned short)(uu[q] & 0xffffu));
      float hi = h2f((unsigned short)(uu[q] >> 16));
      int j = i * 8 + q * 2;
      o0 += lo * w0[j] + hi * w0[j + 1];
      o1 += lo * w1[j] + hi * w1[j + 1];
    }
  }
  *(float2*)(out + (size_t)b * 2) = make_float2(o0, o1);
}

// ---------------------------------------------------------------------------
extern "C" void kernel_launch(void* const* d_in, const int* in_sizes, int n_in,
                              void* d_out, int out_size, void* d_ws, size_t ws_size,
                              hipStream_t stream) {
  const int*   n_id   = (const int*)d_in[0];
  const float* memory = (const float*)d_in[1];
  const int*   last_u = (const int*)d_in[2];
  const int*   s_src  = (const int*)d_in[3];
  const int*   s_dst  = (const int*)d_in[4];
  const int*   s_t    = (const int*)d_in[5];
  const float* s_msg  = (const float*)d_in[6];
  const float* time_w = (const float*)d_in[7];
  const float* time_b = (const float*)d_in[8];
  const float* W_ih   = (const float*)d_in[9];
  const float* b_ih   = (const float*)d_in[10];
  const float* W_hh   = (const float*)d_in[11];
  const float* b_hh   = (const float*)d_in[12];
  const float* W1     = (const float*)d_in[13];
  const float* b1     = (const float*)d_in[14];
  const float* gamma  = (const float*)d_in[15];
  const float* beta   = (const float*)d_in[16];
  const float* W2     = (const float*)d_in[17];
  const float* b2     = (const float*)d_in[18];

  char* ws = (char*)d_ws;
  float*          stats_g = (float*)ws;                                   // 512 B
  float*          biasbuf = (float*)(ws + 512);                           // 1600 B
  unsigned short* Bfrag   = (unsigned short*)(ws + 4096);                 // 270 KiB
  unsigned short* W1frag  = (unsigned short*)(ws + 4096 + 276480);        // 16 KiB
  unsigned short* a_ws    = (unsigned short*)(ws + (1u << 20));           // 32 MiB

  prep_kernel<<<73, 256, 0, stream>>>(W_ih, W_hh, W1, b_ih, b_hh, Bfrag, W1frag,
                                      biasbuf, stats_g);
  main_kernel<<<4096, 256, 0, stream>>>(n_id, memory, last_u, s_src, s_dst, s_t,
                                        s_msg, time_w, time_b, b1,
                                        Bfrag, W1frag, biasbuf, a_ws, stats_g);
  out_kernel<<<1024, 256, 0, stream>>>(a_ws, stats_g, gamma, beta, W2, b2, (float*)d_out);
}